// Round 3
// baseline (284.564 us; speedup 1.0000x reference)
//
#include <hip/hip_runtime.h>
#include <math.h>

// ---- pass1 geometry ------------------------------------------------------
// NB1 * F4_PER_BLOCK == N/4 == 2^23   (2048 * 4096 = 8388608)
#define NB1 2048          // pass1 grid
#define BS 256            // pass1 block size (4 waves)
#define NBATCH 8          // batches per block
#define F4B 512           // float4 (and int4) elements staged per batch per block (8 KB each)
#define F4_PER_BLOCK (NBATCH * F4B)   // 4096 float4 per block
#define P2BS 512          // pass2 block size

typedef float __attribute__((ext_vector_type(4))) vfloat4;
typedef int   __attribute__((ext_vector_type(4))) vint4;

// Async global->LDS DMA (no VGPR writeback). LDS dest is wave-uniform base +
// lane*16; global src is per-lane. vmcnt-counted like a normal VMEM op.
typedef const __attribute__((address_space(1))) void GAS;
typedef __attribute__((address_space(3))) void LAS;
#define GLDS(g, l) __builtin_amdgcn_global_load_lds((GAS*)(g), (LAS*)(l), 16, 0, 0)

// Partials layout in d_ws (doubles), stride NB1:
// [0) sum_all  [1) sum0  [2) cnt0  [3) min  [4) max

__global__ __launch_bounds__(BS) void risk_pass1(const float* __restrict__ x,
                                                 const int* __restrict__ y,
                                                 double* __restrict__ ws) {
    const vfloat4* __restrict__ x4 = (const vfloat4*)x;
    const vint4*   __restrict__ y4 = (const vint4*)y;

    // Double-buffered staging: 2 x (8 KB x + 8 KB y) = 32 KB LDS -> 5 blocks/CU.
    __shared__ vfloat4 lx[2][F4B];
    __shared__ vint4   ly[2][F4B];

    const int t    = threadIdx.x;
    const int w64  = t & ~63;                       // wave-uniform lane-group base
    const int gchunk = blockIdx.x * F4_PER_BLOCK;   // block's first float4 index

    double sum = 0.0, sum0 = 0.0;
    int    cnt0 = 0;
    float  mn =  INFINITY, mx = -INFINITY;

    // Issue one batch's DMA: 4 wave-instrs/wave (2 x-slots + 2 y-slots).
    auto stage = [&](int b, int buf) {
        const int g = gchunk + b * F4B;
        GLDS(&x4[g + t],        &lx[buf][w64]);
        GLDS(&x4[g + 256 + t],  &lx[buf][256 + w64]);
        GLDS(&y4[g + t],        &ly[buf][w64]);
        GLDS(&y4[g + 256 + t],  &ly[buf][256 + w64]);
    };

    stage(0, 0);   // prologue

    #pragma unroll 2
    for (int b = 0; b < NBATCH; ++b) {
        const int buf = b & 1;
        if (b + 1 < NBATCH) {
            stage(b + 1, buf ^ 1);
            // The 4 newest DMAs (batch b+1) stay in flight; batch b has landed.
            asm volatile("s_waitcnt vmcnt(4)" ::: "memory");
        } else {
            asm volatile("s_waitcnt vmcnt(0)" ::: "memory");
        }
        __builtin_amdgcn_sched_barrier(0);
        __builtin_amdgcn_s_barrier();        // all waves' batch-b DMAs landed
        asm volatile("" ::: "memory");

        // Consume 2 float4 + 2 int4 per thread from LDS (ds_read_b128 pairs).
        vfloat4 v0 = lx[buf][t];
        vfloat4 v1 = lx[buf][256 + t];
        vint4   u0 = ly[buf][t];
        vint4   u1 = ly[buf][256 + t];

        float s0 = (v0.x + v0.y) + (v0.z + v0.w);
        float s1 = (v1.x + v1.y) + (v1.z + v1.w);
        float a0 = (u0.x == 0) ? v0.x : 0.0f;
        float b0_ = (u0.y == 0) ? v0.y : 0.0f;
        float c0 = (u0.z == 0) ? v0.z : 0.0f;
        float d0 = (u0.w == 0) ? v0.w : 0.0f;
        float a1 = (u1.x == 0) ? v1.x : 0.0f;
        float b1_ = (u1.y == 0) ? v1.y : 0.0f;
        float c1 = (u1.z == 0) ? v1.z : 0.0f;
        float d1 = (u1.w == 0) ? v1.w : 0.0f;
        float t0 = (a0 + b0_) + (c0 + d0);
        float t1 = (a1 + b1_) + (c1 + d1);
        int   c  = (u0.x == 0) + (u0.y == 0) + (u0.z == 0) + (u0.w == 0)
                 + (u1.x == 0) + (u1.y == 0) + (u1.z == 0) + (u1.w == 0);
        float bmn = fminf(fminf(fminf(v0.x, v0.y), fminf(v0.z, v0.w)),
                          fminf(fminf(v1.x, v1.y), fminf(v1.z, v1.w)));
        float bmx = fmaxf(fmaxf(fmaxf(v0.x, v0.y), fmaxf(v0.z, v0.w)),
                          fmaxf(fmaxf(v1.x, v1.y), fmaxf(v1.z, v1.w)));

        sum  += (double)(s0 + s1);
        sum0 += (double)(t0 + t1);
        cnt0 += c;
        mn = fminf(mn, bmn);
        mx = fmaxf(mx, bmx);

        asm volatile("" ::: "memory");
        __builtin_amdgcn_s_barrier();        // buf may be overwritten next iter
    }

    // wave (64-lane) reduction
    for (int off = 32; off > 0; off >>= 1) {
        sum  += __shfl_down(sum,  off);
        sum0 += __shfl_down(sum0, off);
        cnt0 += __shfl_down(cnt0, off);
        mn = fminf(mn, __shfl_down(mn, off));
        mx = fmaxf(mx, __shfl_down(mx, off));
    }

    __shared__ double s_sum[BS / 64], s_sum0[BS / 64];
    __shared__ int    s_cnt[BS / 64];
    __shared__ float  s_mn[BS / 64], s_mx[BS / 64];

    int lane = threadIdx.x & 63;
    int wave = threadIdx.x >> 6;
    if (lane == 0) {
        s_sum[wave] = sum; s_sum0[wave] = sum0; s_cnt[wave] = cnt0;
        s_mn[wave] = mn; s_mx[wave] = mx;
    }
    __syncthreads();

    if (threadIdx.x == 0) {
        double bsum = s_sum[0], bsum0 = s_sum0[0];
        int bcnt = s_cnt[0];
        float bmn = s_mn[0], bmx = s_mx[0];
        #pragma unroll
        for (int w = 1; w < BS / 64; ++w) {
            bsum += s_sum[w]; bsum0 += s_sum0[w]; bcnt += s_cnt[w];
            bmn = fminf(bmn, s_mn[w]); bmx = fmaxf(bmx, s_mx[w]);
        }
        ws[0 * NB1 + blockIdx.x] = bsum;
        ws[1 * NB1 + blockIdx.x] = bsum0;
        ws[2 * NB1 + blockIdx.x] = (double)bcnt;
        ws[3 * NB1 + blockIdx.x] = (double)bmn;
        ws[4 * NB1 + blockIdx.x] = (double)bmx;
    }
}

__global__ __launch_bounds__(P2BS) void risk_pass2(const double* __restrict__ ws,
                                                   float* __restrict__ out,
                                                   long long n_total) {
    double sum = 0.0, sum0 = 0.0, cnt0 = 0.0;
    double mn =  INFINITY;
    double mx = -INFINITY;

    for (int i = threadIdx.x; i < NB1; i += P2BS) {
        sum  += ws[0 * NB1 + i];
        sum0 += ws[1 * NB1 + i];
        cnt0 += ws[2 * NB1 + i];
        mn = fmin(mn, ws[3 * NB1 + i]);
        mx = fmax(mx, ws[4 * NB1 + i]);
    }

    for (int off = 32; off > 0; off >>= 1) {
        sum  += __shfl_down(sum,  off);
        sum0 += __shfl_down(sum0, off);
        cnt0 += __shfl_down(cnt0, off);
        mn = fmin(mn, __shfl_down(mn, off));
        mx = fmax(mx, __shfl_down(mx, off));
    }

    __shared__ double s_sum[P2BS / 64], s_sum0[P2BS / 64], s_cnt[P2BS / 64];
    __shared__ double s_mn[P2BS / 64], s_mx[P2BS / 64];
    int lane = threadIdx.x & 63;
    int wave = threadIdx.x >> 6;
    if (lane == 0) {
        s_sum[wave] = sum; s_sum0[wave] = sum0; s_cnt[wave] = cnt0;
        s_mn[wave] = mn; s_mx[wave] = mx;
    }
    __syncthreads();

    if (threadIdx.x == 0) {
        double tsum = s_sum[0], tsum0 = s_sum0[0], tcnt0 = s_cnt[0];
        double tmn = s_mn[0], tmx = s_mx[0];
        #pragma unroll
        for (int w = 1; w < P2BS / 64; ++w) {
            tsum += s_sum[w]; tsum0 += s_sum0[w]; tcnt0 += s_cnt[w];
            tmn = fmin(tmn, s_mn[w]); tmx = fmax(tmx, s_mx[w]);
        }
        double range = tmx - tmn;
        double n1 = (double)n_total - tcnt0;
        double sum1 = tsum - tsum0;
        double m0 = (tsum0 / tcnt0 - tmn) / range;
        double m1 = (sum1  / n1    - tmn) / range;
        double l = fmin(m0, m1) - fmax(m0, m1);  // = -|m0 - m1|
        out[0] = (float)l;
    }
}

extern "C" void kernel_launch(void* const* d_in, const int* in_sizes, int n_in,
                              void* d_out, int out_size, void* d_ws, size_t ws_size,
                              hipStream_t stream) {
    const float* x = (const float*)d_in[0];
    const int*   y = (const int*)d_in[1];
    float* out = (float*)d_out;
    double* ws = (double*)d_ws;
    long long n = (long long)in_sizes[0];  // 33554432 == NB1*F4_PER_BLOCK*4

    risk_pass1<<<NB1, BS, 0, stream>>>(x, y, ws);
    risk_pass2<<<1, P2BS, 0, stream>>>(ws, out, n);
}